// Round 10
// baseline (154.531 us; speedup 1.0000x reference)
//
#include <hip/hip_runtime.h>

#define S_LEN 4096
#define BATCH 2
#define DM 512
#define NH 8
#define DH 64
#define WINDOW 256

typedef __bf16 bf16x8 __attribute__((ext_vector_type(8)));
typedef float f32x4 __attribute__((ext_vector_type(4)));
typedef unsigned short u16x8 __attribute__((ext_vector_type(8)));

typedef const __attribute__((address_space(1))) unsigned int* gas_ptr;
typedef __attribute__((address_space(3))) unsigned int* las_ptr;

#define SCALE_LOG2E 0.1803368801111204f  // 0.125 * log2(e)
#define FIXED_MAX 16.0f                  // safe upper bound for log2-domain scores

// native gfx950 bf16 convert, RNE
__device__ __forceinline__ unsigned short b16(float f) {
  __bf16 h = (__bf16)f;
  return __builtin_bit_cast(unsigned short, h);
}

// One fused fp32->bf16 convert for x, qkv_w, out_w (contiguous dest regions).
#define N4_X (8192 * 512 / 4)
#define N4_QW (1536 * 512 / 4)
#define N4_OW (512 * 512 / 4)
__global__ __launch_bounds__(256) void convert_all(const float* __restrict__ x,
                                                   const float* __restrict__ qw,
                                                   const float* __restrict__ ow,
                                                   unsigned short* __restrict__ dst) {
  const int i = blockIdx.x * blockDim.x + threadIdx.x;  // exact grid, one float4 each
  const float4* src;
  int off;
  if (i < N4_X) { src = (const float4*)x; off = 0; }
  else if (i < N4_X + N4_QW) { src = (const float4*)qw; off = N4_X; }
  else { src = (const float4*)ow; off = N4_X + N4_QW; }
  const float4 v = src[i - off];
  ushort4 o;
  o.x = b16(v.x); o.y = b16(v.y); o.z = b16(v.z); o.w = b16(v.w);
  ((ushort4*)dst)[i] = o;
}

// m97-style K-loop (proven R4 structure): C128x128 = A[128x512] * B[128x512]^T,
// BK=32, global_load_lds width-16 staging, 16x16x32 MFMA, 4 waves.
__device__ __forceinline__ void gemm_core(const unsigned short* __restrict__ A,
                                          const unsigned short* __restrict__ Bm,
                                          int m0, int n0,
                                          unsigned short* sA, unsigned short* sB,
                                          f32x4 acc[4][4]) {
  const int t = threadIdx.x;
  const int wave = t >> 6, lane = t & 63;
  const int wr = wave >> 1, wc = wave & 1;
  const int quad = lane >> 4, l16 = lane & 15;

  for (int k0 = 0; k0 < 512; k0 += 32) {
#pragma unroll
    for (int p = 0; p < 2; ++p) {
      const int ci = wave * 128 + p * 64 + lane;   // 16B chunk id, lane-contiguous
      const int row = ci >> 2, cg = ci & 3;
      const unsigned short* ga = A + (size_t)(m0 + row) * 512 + k0 + cg * 8;
      __builtin_amdgcn_global_load_lds((gas_ptr)(const void*)ga,
                                       (las_ptr)(void*)(sA + wave * 1024 + p * 512), 16, 0, 0);
      const unsigned short* gb = Bm + (size_t)(n0 + row) * 512 + k0 + cg * 8;
      __builtin_amdgcn_global_load_lds((gas_ptr)(const void*)gb,
                                       (las_ptr)(void*)(sB + wave * 1024 + p * 512), 16, 0, 0);
    }
    __syncthreads();
    bf16x8 af[4], bff[4];
#pragma unroll
    for (int i = 0; i < 4; ++i)
      af[i] = *(const bf16x8*)&sA[(wr * 64 + i * 16 + l16) * 32 + quad * 8];
#pragma unroll
    for (int j = 0; j < 4; ++j)
      bff[j] = *(const bf16x8*)&sB[(wc * 64 + j * 16 + l16) * 32 + quad * 8];
#pragma unroll
    for (int i = 0; i < 4; ++i)
#pragma unroll
      for (int j = 0; j < 4; ++j)
        acc[i][j] = __builtin_amdgcn_mfma_f32_16x16x32_bf16(af[i], bff[j], acc[i][j], 0, 0, 0);
    __syncthreads();
  }
}

// QKV projection: Q (pre-scaled by SCALE_LOG2E) -> Qb[B*S][512],
// K -> Kb[B*S][512], V -> Vt[b][h][d][S]
__global__ __launch_bounds__(256) void gemm_qkv(const unsigned short* __restrict__ xb,
                                                const unsigned short* __restrict__ wb,
                                                const float* __restrict__ bias,
                                                unsigned short* __restrict__ Qb,
                                                unsigned short* __restrict__ Kb,
                                                unsigned short* __restrict__ Vt) {
  __shared__ __align__(16) unsigned short sA[128 * 32];
  __shared__ __align__(16) unsigned short sB[128 * 32];
  f32x4 acc[4][4] = {};
  const int m0 = blockIdx.y * 128, n0 = blockIdx.x * 128;
  gemm_core(xb, wb, m0, n0, sA, sB, acc);

  const int t = threadIdx.x;
  const int wave = t >> 6, lane = t & 63;
  const int wr = wave >> 1, wc = wave & 1;
  const int quad = lane >> 4, l16 = lane & 15;
#pragma unroll
  for (int j = 0; j < 4; ++j) {
    const int n = n0 + wc * 64 + j * 16 + l16;
    const float bv = bias[n];
#pragma unroll
    for (int i = 0; i < 4; ++i) {
      const int mr = m0 + wr * 64 + i * 16 + quad * 4;
      if (n < DM) {
#pragma unroll
        for (int r = 0; r < 4; ++r)
          Qb[(size_t)(mr + r) * DM + n] = b16((acc[i][j][r] + bv) * SCALE_LOG2E);
      } else if (n < 2 * DM) {
#pragma unroll
        for (int r = 0; r < 4; ++r)
          Kb[(size_t)(mr + r) * DM + (n - DM)] = b16(acc[i][j][r] + bv);
      } else {
        const int d = n & 63, h = (n - 2 * DM) >> 6;
#pragma unroll
        for (int r = 0; r < 4; ++r) {
          const int m = mr + r;
          const int b = m >> 12, s = m & (S_LEN - 1);
          Vt[((size_t)((b * NH + h) * DH + d)) * S_LEN + s] = b16(acc[i][j][r] + bv);
        }
      }
    }
  }
}

// Output projection, 64x128 tile (grid 512 = 2 blocks/CU so barrier drains
// overlap across blocks; the old 128x128 grid was 256 = exactly 1/CU).
__global__ __launch_bounds__(256) void gemm_out(const unsigned short* __restrict__ Ab,
                                                const unsigned short* __restrict__ wb,
                                                const float* __restrict__ bias,
                                                float* __restrict__ C) {
  __shared__ __align__(16) unsigned short sA[64 * 32];
  __shared__ __align__(16) unsigned short sB[128 * 32];
  const int t = threadIdx.x;
  const int wave = t >> 6, lane = t & 63;
  const int wr = wave >> 1, wc = wave & 1;
  const int quad = lane >> 4, l16 = lane & 15;
  const int m0 = blockIdx.y * 64, n0 = blockIdx.x * 128;

  f32x4 acc[2][4] = {};
  for (int k0 = 0; k0 < 512; k0 += 32) {
    {  // A: 64x32 = 256 chunks, 1/thread
      const int row = t >> 2, cg = t & 3;
      const unsigned short* ga = Ab + (size_t)(m0 + row) * 512 + k0 + cg * 8;
      __builtin_amdgcn_global_load_lds((gas_ptr)(const void*)ga,
                                       (las_ptr)(void*)(sA + wave * 512), 16, 0, 0);
    }
#pragma unroll
    for (int p = 0; p < 2; ++p) {  // B: 128x32 = 512 chunks, 2/thread
      const int ci = wave * 128 + p * 64 + lane;
      const int row = ci >> 2, cg = ci & 3;
      const unsigned short* gb = wb + (size_t)(n0 + row) * 512 + k0 + cg * 8;
      __builtin_amdgcn_global_load_lds((gas_ptr)(const void*)gb,
                                       (las_ptr)(void*)(sB + wave * 1024 + p * 512), 16, 0, 0);
    }
    __syncthreads();
    bf16x8 af[2], bff[4];
#pragma unroll
    for (int i = 0; i < 2; ++i)
      af[i] = *(const bf16x8*)&sA[(wr * 32 + i * 16 + l16) * 32 + quad * 8];
#pragma unroll
    for (int j = 0; j < 4; ++j)
      bff[j] = *(const bf16x8*)&sB[(wc * 64 + j * 16 + l16) * 32 + quad * 8];
#pragma unroll
    for (int i = 0; i < 2; ++i)
#pragma unroll
      for (int j = 0; j < 4; ++j)
        acc[i][j] = __builtin_amdgcn_mfma_f32_16x16x32_bf16(af[i], bff[j], acc[i][j], 0, 0, 0);
    __syncthreads();
  }

#pragma unroll
  for (int j = 0; j < 4; ++j) {
    const int n = n0 + wc * 64 + j * 16 + l16;
    const float bv = bias[n];
#pragma unroll
    for (int i = 0; i < 2; ++i) {
      const int mr = m0 + wr * 32 + i * 16 + quad * 4;
#pragma unroll
      for (int r = 0; r < 4; ++r)
        C[(size_t)(mr + r) * DM + n] = acc[i][j][r] + bv;
    }
  }
}

// Barrier-free MFMA flash attention. All K/V fragments come straight from
// global (A/B share the [row=l16][k=quad*8+j] layout; each wave's frag loads
// consume whole 64B lines; 4x wave redundancy is L1/L2-absorbed). PV is
// computed operand-swapped: O^T = V^T * P^T, so P's A-layout LDS image is the
// B operand unchanged and the output store packs 8B. No __syncthreads at all:
// the only LDS is the per-wave P round-trip and a 64-float l-broadcast slab.
// Fixed-max softmax (Q pre-scaled by SCALE_LOG2E): p = exp2(s - 16).
__global__ __launch_bounds__(256) void attn_mfma(const unsigned short* __restrict__ Qb,
                                                 const unsigned short* __restrict__ Kb,
                                                 const unsigned short* __restrict__ Vt,
                                                 unsigned short* __restrict__ AO) {
  __shared__ __align__(16) unsigned short Ps[64 * 72];
  __shared__ float Ls[64];
  const int t = threadIdx.x;
  const int wave = t >> 6, lane = t & 63;
  const int quad = lane >> 4, l16 = lane & 15;
  const int q0 = blockIdx.x * 64, h = blockIdx.y, b = blockIdx.z;

  const unsigned short* Kbase = Kb + (size_t)b * S_LEN * DM + h * DH;
  const unsigned short* Vbase = Vt + (size_t)((b * NH + h) * DH) * S_LEN;

  // Q A-fragments from global, loop-invariant (Q pre-scaled by SCALE_LOG2E)
  const unsigned short* qrow =
      Qb + (size_t)(b * S_LEN + q0 + wave * 16 + l16) * DM + h * DH;
  const bf16x8 aq0 = *(const bf16x8*)(qrow + quad * 8);
  const bf16x8 aq1 = *(const bf16x8*)(qrow + 32 + quad * 8);

  const int first = (q0 >= WINDOW) ? 0 : (4 - blockIdx.x);  // first valid chunk

  float l_[4];
  f32x4 Ot[4] = {};  // O^T: m = d (4 tiles of 16), n = q-row = l16
#pragma unroll
  for (int r = 0; r < 4; ++r) l_[r] = 0.f;

#pragma unroll
  for (int c = 0; c < 5; ++c) {
    if (c < first) continue;  // block-uniform
    const int c0 = q0 - WINDOW + c * 64;

    // K B-frags: rows nt*16+l16, k = kh*32 + quad*8 (whole 64B lines per row)
    bf16x8 bk[4][2];
#pragma unroll
    for (int nt = 0; nt < 4; ++nt)
#pragma unroll
      for (int kh = 0; kh < 2; ++kh)
        bk[nt][kh] = *(const bf16x8*)(Kbase + (size_t)(c0 + nt * 16 + l16) * DM +
                                      kh * 32 + quad * 8);

    // S = Q K^T (this wave's 16 q-rows x 64 keys)
    f32x4 sc[4];
#pragma unroll
    for (int nt = 0; nt < 4; ++nt) {
      f32x4 z = {};
      z = __builtin_amdgcn_mfma_f32_16x16x32_bf16(aq0, bk[nt][0], z, 0, 0, 0);
      sc[nt] = __builtin_amdgcn_mfma_f32_16x16x32_bf16(aq1, bk[nt][1], z, 0, 0, 0);
    }

    // V^T A-frags (issued here so latency overlaps exp2/pack below)
    bf16x8 av[4][2];
#pragma unroll
    for (int nt = 0; nt < 4; ++nt)
#pragma unroll
      for (int kh = 0; kh < 2; ++kh)
        av[nt][kh] = *(const bf16x8*)(Vbase + (size_t)(nt * 16 + l16) * S_LEN +
                                      c0 + kh * 32 + quad * 8);

    // p = exp2(s - 16), masked to 0 on boundary chunks (c is compile-time)
#pragma unroll
    for (int nt = 0; nt < 4; ++nt) {
      const int jj = nt * 16 + l16;
#pragma unroll
      for (int r = 0; r < 4; ++r) {
        const int ii = wave * 16 + quad * 4 + r;
        float p = exp2f(sc[nt][r] - FIXED_MAX);
        if (c == 0) p = (jj >= ii) ? p : 0.f;
        if (c == 4) p = (jj <= ii) ? p : 0.f;
        sc[nt][r] = p;
        l_[r] += p;
      }
    }

    // P: C-layout -> A/B-layout via LDS, own wave's rows only (wave-lockstep)
#pragma unroll
    for (int nt = 0; nt < 4; ++nt)
#pragma unroll
      for (int r = 0; r < 4; ++r)
        Ps[(wave * 16 + quad * 4 + r) * 72 + nt * 16 + l16] = b16(sc[nt][r]);

    const bf16x8 bp0 = *(const bf16x8*)&Ps[(wave * 16 + l16) * 72 + quad * 8];
    const bf16x8 bp1 = *(const bf16x8*)&Ps[(wave * 16 + l16) * 72 + 32 + quad * 8];

    // O^T += V^T P^T  (A = V^T frag, B = P in A-layout; same-shape operands)
#pragma unroll
    for (int nt = 0; nt < 4; ++nt) {
      Ot[nt] = __builtin_amdgcn_mfma_f32_16x16x32_bf16(av[nt][0], bp0, Ot[nt], 0, 0, 0);
      Ot[nt] = __builtin_amdgcn_mfma_f32_16x16x32_bf16(av[nt][1], bp1, Ot[nt], 0, 0, 0);
    }
  }

  // denominator: reduce over the 16 col-lanes, then broadcast row-major -> col-major
#pragma unroll
  for (int off = 1; off <= 8; off <<= 1)
#pragma unroll
    for (int r = 0; r < 4; ++r) l_[r] += __shfl_xor(l_[r], off);
  if (l16 == 0) {
#pragma unroll
    for (int r = 0; r < 4; ++r) Ls[wave * 16 + quad * 4 + r] = l_[r];
  }
  const float linv = 1.f / Ls[wave * 16 + l16];  // same-wave DS order guarantees visibility

  // O^T C-layout: lane holds q-row i = l16, d = nt*16 + quad*4 + r -> 8B packed
  unsigned short* aoRow = AO + (size_t)(b * S_LEN + q0 + wave * 16 + l16) * DM + h * DH;
#pragma unroll
  for (int nt = 0; nt < 4; ++nt) {
    ushort4 o;
    o.x = b16(Ot[nt][0] * linv);
    o.y = b16(Ot[nt][1] * linv);
    o.z = b16(Ot[nt][2] * linv);
    o.w = b16(Ot[nt][3] * linv);
    *(ushort4*)(aoRow + nt * 16 + quad * 4) = o;
  }
}

extern "C" void kernel_launch(void* const* d_in, const int* in_sizes, int n_in,
                              void* d_out, int out_size, void* d_ws, size_t ws_size,
                              hipStream_t stream) {
  const float* x = (const float*)d_in[0];
  const float* qkv_w = (const float*)d_in[1];
  const float* qkv_b = (const float*)d_in[2];
  const float* out_w = (const float*)d_in[3];
  const float* out_b = (const float*)d_in[4];
  float* out = (float*)d_out;

  const int M = BATCH * S_LEN;  // 8192
  unsigned short* ws = (unsigned short*)d_ws;
  unsigned short* xb   = ws;                      // 8192*512
  unsigned short* wqkv = xb + (size_t)M * DM;     // 1536*512
  unsigned short* wout = wqkv + 3 * DM * DM;      // 512*512
  unsigned short* Qb   = wout + DM * DM;          // 8192*512
  unsigned short* Kb   = Qb + (size_t)M * DM;     // 8192*512
  unsigned short* Vt   = Kb + (size_t)M * DM;     // 2*8*64*4096
  unsigned short* AO   = Vt + (size_t)M * DM;     // 8192*512

  convert_all<<<(N4_X + N4_QW + N4_OW) / 256, 256, 0, stream>>>(x, qkv_w, out_w, xb);

  gemm_qkv<<<dim3(12, 64), 256, 0, stream>>>(xb, wqkv, qkv_b, Qb, Kb, Vt);

  attn_mfma<<<dim3(S_LEN / 64, NH, BATCH), 256, 0, stream>>>(Qb, Kb, Vt, AO);

  gemm_out<<<dim3(4, 128), 256, 0, stream>>>(AO, wout, out_b, out);
}

// Round 11
// 136.231 us; speedup vs baseline: 1.1343x; 1.1343x over previous
//
#include <hip/hip_runtime.h>

#define S_LEN 4096
#define BATCH 2
#define DM 512
#define NH 8
#define DH 64
#define WINDOW 256

typedef __bf16 bf16x8 __attribute__((ext_vector_type(8)));
typedef float f32x4 __attribute__((ext_vector_type(4)));
typedef unsigned short u16x8 __attribute__((ext_vector_type(8)));

typedef const __attribute__((address_space(1))) unsigned int* gas_ptr;
typedef __attribute__((address_space(3))) unsigned int* las_ptr;

#define SCALE_LOG2E 0.1803368801111204f  // 0.125 * log2(e)
#define FIXED_MAX 16.0f                  // safe upper bound for log2-domain scores

// native gfx950 bf16 convert, RNE
__device__ __forceinline__ unsigned short b16(float f) {
  __bf16 h = (__bf16)f;
  return __builtin_bit_cast(unsigned short, h);
}

// One fused fp32->bf16 convert for x, qkv_w, out_w (contiguous dest regions).
#define N4_X (8192 * 512 / 4)
#define N4_QW (1536 * 512 / 4)
#define N4_OW (512 * 512 / 4)
__global__ __launch_bounds__(256) void convert_all(const float* __restrict__ x,
                                                   const float* __restrict__ qw,
                                                   const float* __restrict__ ow,
                                                   unsigned short* __restrict__ dst) {
  const int i = blockIdx.x * blockDim.x + threadIdx.x;  // exact grid, one float4 each
  const float4* src;
  int off;
  if (i < N4_X) { src = (const float4*)x; off = 0; }
  else if (i < N4_X + N4_QW) { src = (const float4*)qw; off = N4_X; }
  else { src = (const float4*)ow; off = N4_X + N4_QW; }
  const float4 v = src[i - off];
  ushort4 o;
  o.x = b16(v.x); o.y = b16(v.y); o.z = b16(v.z); o.w = b16(v.w);
  ((ushort4*)dst)[i] = o;
}

// m97-style K-loop (proven R4 structure): C128x128 = A[128x512] * B[128x512]^T,
// BK=32, global_load_lds width-16 staging, 16x16x32 MFMA, 4 waves.
__device__ __forceinline__ void gemm_core(const unsigned short* __restrict__ A,
                                          const unsigned short* __restrict__ Bm,
                                          int m0, int n0,
                                          unsigned short* sA, unsigned short* sB,
                                          f32x4 acc[4][4]) {
  const int t = threadIdx.x;
  const int wave = t >> 6, lane = t & 63;
  const int wr = wave >> 1, wc = wave & 1;
  const int quad = lane >> 4, l16 = lane & 15;

  for (int k0 = 0; k0 < 512; k0 += 32) {
#pragma unroll
    for (int p = 0; p < 2; ++p) {
      const int ci = wave * 128 + p * 64 + lane;   // 16B chunk id, lane-contiguous
      const int row = ci >> 2, cg = ci & 3;
      const unsigned short* ga = A + (size_t)(m0 + row) * 512 + k0 + cg * 8;
      __builtin_amdgcn_global_load_lds((gas_ptr)(const void*)ga,
                                       (las_ptr)(void*)(sA + wave * 1024 + p * 512), 16, 0, 0);
      const unsigned short* gb = Bm + (size_t)(n0 + row) * 512 + k0 + cg * 8;
      __builtin_amdgcn_global_load_lds((gas_ptr)(const void*)gb,
                                       (las_ptr)(void*)(sB + wave * 1024 + p * 512), 16, 0, 0);
    }
    __syncthreads();
    bf16x8 af[4], bff[4];
#pragma unroll
    for (int i = 0; i < 4; ++i)
      af[i] = *(const bf16x8*)&sA[(wr * 64 + i * 16 + l16) * 32 + quad * 8];
#pragma unroll
    for (int j = 0; j < 4; ++j)
      bff[j] = *(const bf16x8*)&sB[(wc * 64 + j * 16 + l16) * 32 + quad * 8];
#pragma unroll
    for (int i = 0; i < 4; ++i)
#pragma unroll
      for (int j = 0; j < 4; ++j)
        acc[i][j] = __builtin_amdgcn_mfma_f32_16x16x32_bf16(af[i], bff[j], acc[i][j], 0, 0, 0);
    __syncthreads();
  }
}

// QKV projection: Q (pre-scaled by SCALE_LOG2E) -> Qb[B*S][512],
// K -> Kb[B*S][512], V -> Vt[b][h][d][S]
__global__ __launch_bounds__(256) void gemm_qkv(const unsigned short* __restrict__ xb,
                                                const unsigned short* __restrict__ wb,
                                                const float* __restrict__ bias,
                                                unsigned short* __restrict__ Qb,
                                                unsigned short* __restrict__ Kb,
                                                unsigned short* __restrict__ Vt) {
  __shared__ __align__(16) unsigned short sA[128 * 32];
  __shared__ __align__(16) unsigned short sB[128 * 32];
  f32x4 acc[4][4] = {};
  const int m0 = blockIdx.y * 128, n0 = blockIdx.x * 128;
  gemm_core(xb, wb, m0, n0, sA, sB, acc);

  const int t = threadIdx.x;
  const int wave = t >> 6, lane = t & 63;
  const int wr = wave >> 1, wc = wave & 1;
  const int quad = lane >> 4, l16 = lane & 15;
#pragma unroll
  for (int j = 0; j < 4; ++j) {
    const int n = n0 + wc * 64 + j * 16 + l16;
    const float bv = bias[n];
#pragma unroll
    for (int i = 0; i < 4; ++i) {
      const int mr = m0 + wr * 64 + i * 16 + quad * 4;
      if (n < DM) {
#pragma unroll
        for (int r = 0; r < 4; ++r)
          Qb[(size_t)(mr + r) * DM + n] = b16((acc[i][j][r] + bv) * SCALE_LOG2E);
      } else if (n < 2 * DM) {
#pragma unroll
        for (int r = 0; r < 4; ++r)
          Kb[(size_t)(mr + r) * DM + (n - DM)] = b16(acc[i][j][r] + bv);
      } else {
        const int d = n & 63, h = (n - 2 * DM) >> 6;
#pragma unroll
        for (int r = 0; r < 4; ++r) {
          const int m = mr + r;
          const int b = m >> 12, s = m & (S_LEN - 1);
          Vt[((size_t)((b * NH + h) * DH + d)) * S_LEN + s] = b16(acc[i][j][r] + bv);
        }
      }
    }
  }
}

// Output projection: C fp32 = AO * wout^T + bias (proven R8 128x128 shape)
__global__ __launch_bounds__(256) void gemm_out(const unsigned short* __restrict__ Ab,
                                                const unsigned short* __restrict__ wb,
                                                const float* __restrict__ bias,
                                                float* __restrict__ C) {
  __shared__ __align__(16) unsigned short sA[128 * 32];
  __shared__ __align__(16) unsigned short sB[128 * 32];
  f32x4 acc[4][4] = {};
  const int m0 = blockIdx.y * 128, n0 = blockIdx.x * 128;
  gemm_core(Ab, wb, m0, n0, sA, sB, acc);

  const int t = threadIdx.x;
  const int wave = t >> 6, lane = t & 63;
  const int wr = wave >> 1, wc = wave & 1;
  const int quad = lane >> 4, l16 = lane & 15;
#pragma unroll
  for (int j = 0; j < 4; ++j) {
    const int n = n0 + wc * 64 + j * 16 + l16;
    const float bv = bias[n];
#pragma unroll
    for (int i = 0; i < 4; ++i) {
      const int mr = m0 + wr * 64 + i * 16 + quad * 4;
#pragma unroll
      for (int r = 0; r < 4; ++r)
        C[(size_t)(mr + r) * DM + n] = acc[i][j][r] + bv;
    }
  }
}

// MFMA flash attention (R8 structure + double-buffered K/V LDS => ONE barrier
// per chunk instead of two). Fixed-max softmax (Q pre-scaled), Q frags in
// registers, register prefetch of next chunk, per-lane partial denominator
// with one final allreduce.
// Safety of the single barrier: a wave writing buffer (c+1)&1 at iter c+1 has
// passed barrier c, which implies all waves finished chunk c-1's compute --
// the only readers of that buffer.
__global__ __launch_bounds__(256) void attn_mfma(const unsigned short* __restrict__ Qb,
                                                 const unsigned short* __restrict__ Kb,
                                                 const unsigned short* __restrict__ Vt,
                                                 unsigned short* __restrict__ AO) {
  __shared__ __align__(16) unsigned short Ks[2][64 * 72];
  __shared__ __align__(16) unsigned short Vs[2][64 * 72];  // V^T chunk: [d][seq]
  __shared__ __align__(16) unsigned short Ps[64 * 72];
  const int t = threadIdx.x;
  const int wave = t >> 6, lane = t & 63;
  const int quad = lane >> 4, l16 = lane & 15;
  const int q0 = blockIdx.x * 64, h = blockIdx.y, b = blockIdx.z;

  const unsigned short* Kbase = Kb + (size_t)b * S_LEN * DM + h * DH;
  const unsigned short* Vbase = Vt + (size_t)((b * NH + h) * DH) * S_LEN;

  // Q A-fragments from global, loop-invariant (Q pre-scaled by SCALE_LOG2E)
  const unsigned short* qrow =
      Qb + (size_t)(b * S_LEN + q0 + wave * 16 + l16) * DM + h * DH;
  const bf16x8 aq0 = *(const bf16x8*)(qrow + quad * 8);
  const bf16x8 aq1 = *(const bf16x8*)(qrow + 32 + quad * 8);

  const int first = (q0 >= WINDOW) ? 0 : (4 - blockIdx.x);  // first valid chunk

  u16x8 kbuf[2][2], vbuf[2][2];
#define LOAD_CHUNK(c0, p)                                                      \
  do {                                                                         \
    _Pragma("unroll") for (int s = 0; s < 2; ++s) {                            \
      const int f = t + 256 * s;                                               \
      const int row = f >> 3, c8 = f & 7;                                      \
      kbuf[p][s] = *(const u16x8*)(Kbase + (size_t)((c0) + row) * DM + c8 * 8);\
      vbuf[p][s] = *(const u16x8*)(Vbase + (size_t)row * S_LEN + (c0) + c8 * 8);\
    }                                                                          \
  } while (0)

#pragma unroll
  for (int c = 0; c < 5; ++c)
    if (c == first) LOAD_CHUNK(q0 - WINDOW + c * 64, c & 1);

  float l_[4];
  f32x4 O[4] = {};
#pragma unroll
  for (int r = 0; r < 4; ++r) l_[r] = 0.f;

#pragma unroll
  for (int c = 0; c < 5; ++c) {
    if (c < first) continue;  // block-uniform
    const int c0 = q0 - WINDOW + c * 64;
    // VGPR -> LDS into buffer c&1 (safe without a leading barrier: see header)
#pragma unroll
    for (int s = 0; s < 2; ++s) {
      const int f = t + 256 * s;
      const int row = f >> 3, c8 = f & 7;
      *(u16x8*)&Ks[c & 1][row * 72 + c8 * 8] = kbuf[c & 1][s];
      *(u16x8*)&Vs[c & 1][row * 72 + c8 * 8] = vbuf[c & 1][s];
    }
    if (c < 4) LOAD_CHUNK(c0 + 64, (c + 1) & 1);  // prefetch next chunk
    __syncthreads();  // this chunk's staging visible to all waves

    // S = Q K^T (this wave's 16 q-rows x 64 keys); Q already carries the scale
    f32x4 sc[4];
#pragma unroll
    for (int nt = 0; nt < 4; ++nt) {
      bf16x8 bk0 = *(const bf16x8*)&Ks[c & 1][(nt * 16 + l16) * 72 + quad * 8];
      bf16x8 bk1 = *(const bf16x8*)&Ks[c & 1][(nt * 16 + l16) * 72 + 32 + quad * 8];
      f32x4 z = {};
      z = __builtin_amdgcn_mfma_f32_16x16x32_bf16(aq0, bk0, z, 0, 0, 0);
      sc[nt] = __builtin_amdgcn_mfma_f32_16x16x32_bf16(aq1, bk1, z, 0, 0, 0);
    }

    // p = exp2(s - 16), masked to 0 on boundary chunks (c is compile-time).
#pragma unroll
    for (int nt = 0; nt < 4; ++nt) {
      const int jj = nt * 16 + l16;
#pragma unroll
      for (int r = 0; r < 4; ++r) {
        const int ii = wave * 16 + quad * 4 + r;
        float p = exp2f(sc[nt][r] - FIXED_MAX);
        if (c == 0) p = (jj >= ii) ? p : 0.f;
        if (c == 4) p = (jj <= ii) ? p : 0.f;
        sc[nt][r] = p;
        l_[r] += p;
      }
    }

    // P: C-layout -> A-layout via LDS, own wave's rows only (no barrier)
#pragma unroll
    for (int nt = 0; nt < 4; ++nt)
#pragma unroll
      for (int r = 0; r < 4; ++r)
        Ps[(wave * 16 + quad * 4 + r) * 72 + nt * 16 + l16] = b16(sc[nt][r]);

    // O += P V (no rescale needed with fixed max)
    bf16x8 ap0 = *(const bf16x8*)&Ps[(wave * 16 + l16) * 72 + quad * 8];
    bf16x8 ap1 = *(const bf16x8*)&Ps[(wave * 16 + l16) * 72 + 32 + quad * 8];
#pragma unroll
    for (int nt = 0; nt < 4; ++nt) {
      bf16x8 bv0 = *(const bf16x8*)&Vs[c & 1][(nt * 16 + l16) * 72 + quad * 8];
      bf16x8 bv1 = *(const bf16x8*)&Vs[c & 1][(nt * 16 + l16) * 72 + 32 + quad * 8];
      O[nt] = __builtin_amdgcn_mfma_f32_16x16x32_bf16(ap0, bv0, O[nt], 0, 0, 0);
      O[nt] = __builtin_amdgcn_mfma_f32_16x16x32_bf16(ap1, bv1, O[nt], 0, 0, 0);
    }
  }

  // one deferred denominator allreduce over the 16-lane row group (bits 0-3)
#pragma unroll
  for (int off = 1; off <= 8; off <<= 1)
#pragma unroll
    for (int r = 0; r < 4; ++r) l_[r] += __shfl_xor(l_[r], off);
#pragma unroll
  for (int r = 0; r < 4; ++r) l_[r] = 1.f / l_[r];

#pragma unroll
  for (int nt = 0; nt < 4; ++nt) {
    const int col = h * DH + nt * 16 + l16;
#pragma unroll
    for (int r = 0; r < 4; ++r) {
      const int m = b * S_LEN + q0 + wave * 16 + quad * 4 + r;
      AO[(size_t)m * DM + col] = b16(O[nt][r] * l_[r]);
    }
  }
}

extern "C" void kernel_launch(void* const* d_in, const int* in_sizes, int n_in,
                              void* d_out, int out_size, void* d_ws, size_t ws_size,
                              hipStream_t stream) {
  const float* x = (const float*)d_in[0];
  const float* qkv_w = (const float*)d_in[1];
  const float* qkv_b = (const float*)d_in[2];
  const float* out_w = (const float*)d_in[3];
  const float* out_b = (const float*)d_in[4];
  float* out = (float*)d_out;

  const int M = BATCH * S_LEN;  // 8192
  unsigned short* ws = (unsigned short*)d_ws;
  unsigned short* xb   = ws;                      // 8192*512
  unsigned short* wqkv = xb + (size_t)M * DM;     // 1536*512
  unsigned short* wout = wqkv + 3 * DM * DM;      // 512*512
  unsigned short* Qb   = wout + DM * DM;          // 8192*512
  unsigned short* Kb   = Qb + (size_t)M * DM;     // 8192*512
  unsigned short* Vt   = Kb + (size_t)M * DM;     // 2*8*64*4096
  unsigned short* AO   = Vt + (size_t)M * DM;     // 8192*512

  convert_all<<<(N4_X + N4_QW + N4_OW) / 256, 256, 0, stream>>>(x, qkv_w, out_w, xb);

  gemm_qkv<<<dim3(12, 64), 256, 0, stream>>>(xb, wqkv, qkv_b, Qb, Kb, Vt);

  attn_mfma<<<dim3(S_LEN / 64, NH, BATCH), 256, 0, stream>>>(Qb, Kb, Vt, AO);

  gemm_out<<<dim3(4, 64), 256, 0, stream>>>(AO, wout, out_b, out);
}